// Round 13
// baseline (627.506 us; speedup 1.0000x reference)
//
#include <hip/hip_runtime.h>
#include <hip/hip_bf16.h>

// PointCloudNetPersistencePrediction — round 13: kill hot-loop stalls.
// R12 flat -> VALU count not binding; per-SIMD ideal ~4-6us vs 15.6 measured
// => stall-bound (just-in-time ds_read->pk waitcnt ~120cyc x32, JIT B-frag
// gather ~300cyc x8, possible ocml exp2 expansion overhead). Fix: 2-deep
// register pipeline (prefetch next kc's 4 e-vectors + B-frag during current
// kc's ~260cyc of pk math) + guaranteed 2-instr inline v_exp_f16.

#define NN 2048
#define NPAIR 16

typedef _Float16 half8 __attribute__((ext_vector_type(8)));
typedef _Float16 f16x2 __attribute__((ext_vector_type(2)));
typedef float f32x4 __attribute__((ext_vector_type(4)));

#define C2F 0.28853900817779268f   //  0.2 * log2(e)
#define CWF -0.14426950408889634f  // -0.1 * log2(e)
#define NL2T 3.3219280948873623f   // -log2(0.1); qi' = qi + NL2T

__device__ __forceinline__ _Float16 exph(_Float16 x) {
    _Float16 r;
    asm("v_exp_f16 %0, %1" : "=v"(r) : "v"(x));
    return r;
}

// ---- init: Xs fp32 [p][i][{x,y,z,q}]; XT fp16 [p][16][2048], row3 = ones ----
__global__ __launch_bounds__(256) void init_k(const float* __restrict__ pc,
                                              const float* __restrict__ alphas,
                                              float* __restrict__ Xs,
                                              _Float16* __restrict__ XT) {
    int gid = blockIdx.x * 256 + threadIdx.x;
    if (gid >= NPAIR * NN) return;
    int p = gid >> 11, i = gid & (NN - 1);
    int b = p >> 2, k = p & 3;
    const float* pcr = pc + ((size_t)b * NN + i) * 3;
    const float* al  = alphas + k * 3;
    float x = pcr[0] * al[0], y = pcr[1] * al[1], z = pcr[2] * al[2];
    float4 o; o.x = x; o.y = y; o.z = z; o.w = CWF * (x * x + y * y + z * z);
    ((float4*)Xs)[gid] = o;
    _Float16* xt = XT + (size_t)p * 16 * NN + i;
    xt[0 * NN] = (_Float16)x;
    xt[1 * NN] = (_Float16)y;
    xt[2 * NN] = (_Float16)z;
    xt[3 * NN] = (_Float16)1.0f;          // ones column -> deg via MFMA
#pragma unroll
    for (int n = 4; n < 16; ++n) xt[n * NN] = (_Float16)0.f;
}

// ---- pack_k: Xp16[p][e] = {x2,y2,z2,q2} fp16 pairs of rows (2e, 2e+1) ----
__global__ __launch_bounds__(256) void pack_k(const float* __restrict__ Xs,
                                              float* __restrict__ Xp) {
    int gid = blockIdx.x * 256 + threadIdx.x;      // p*1024 + e
    if (gid >= NPAIR * 1024) return;
    float4 a = ((const float4*)Xs)[2 * gid];
    float4 b = ((const float4*)Xs)[2 * gid + 1];
    union { f16x2 h[4]; float4 f; } o;
    o.h[0] = (f16x2){(_Float16)a.x, (_Float16)b.x};
    o.h[1] = (f16x2){(_Float16)a.y, (_Float16)b.y};
    o.h[2] = (f16x2){(_Float16)a.z, (_Float16)b.z};
    o.h[3] = (f16x2){(_Float16)a.w, (_Float16)b.w};
    ((float4*)Xp)[gid] = o.f;
}

// ---- fused apply: Ct = f16(0.5*Bt + ihd (x) (W@Bt^T)^T), W recomputed ----
// block = 512 thr = 8 waves (K-chunk 256 each); lane owns 4 m-subtiles.
// Fragments hold 10*w; epilogue uses 0.1*ih (exact fold via 2^3.32=10).
template<bool FIRST>
__global__ __launch_bounds__(512, 4) void fused_apply_k(const float* __restrict__ Xs,
                                                        const float* __restrict__ Xp,
                                                        float* __restrict__ ihd,
                                                        const _Float16* __restrict__ Bt,
                                                        _Float16* __restrict__ Ct,
                                                        float* __restrict__ lvl,
                                                        int t) {
    __shared__ __align__(16) float smem[8192];     // 16KB packed X stage / 32KB red
    const int tid  = threadIdx.x;
    const int lane = tid & 63;
    const int wv   = tid >> 6;                     // K-group 0..7
    const int p    = blockIdx.y;
    const int m0   = blockIdx.x * 64;
    const int idx16 = lane & 15, quad = lane >> 4;

    // stage packed X[p] into LDS: 1024 float4 entries (2 per thread)
    {
        const float4* src = (const float4*)(Xp + (size_t)p * 1024 * 4);
        float4* dst = (float4*)smem;
        dst[tid]       = src[tid];
        dst[tid + 512] = src[tid + 512];
    }
    __syncthreads();

    // per-lane row constants (fp16 broadcast pairs), from fp32 Xs
    f16x2 qi2[4], xx2[4], xy2[4], xz2[4];
#pragma unroll
    for (int s = 0; s < 4; ++s) {
        float4 v = *(const float4*)(Xs + ((size_t)p * NN + m0 + s * 16 + idx16) * 4);
        _Float16 q = (_Float16)(v.w + NL2T);
        _Float16 x = (_Float16)(C2F * v.x);
        _Float16 y = (_Float16)(C2F * v.y);
        _Float16 z = (_Float16)(C2F * v.z);
        qi2[s] = (f16x2){q, q};
        xx2[s] = (f16x2){x, x};
        xy2[s] = (f16x2){y, y};
        xz2[s] = (f16x2){z, z};
    }
    const f16x2 SC2 = (f16x2){(_Float16)32768.f, (_Float16)32768.f};

    const _Float16* bp = Bt + ((size_t)p * 16 + idx16) * NN + wv * 256 + quad * 8;
    const int pbase = wv * 128 + quad * 4;         // j-pair entry base (kc=0)
    f32x4 acc[4] = {{0.f,0.f,0.f,0.f},{0.f,0.f,0.f,0.f},
                    {0.f,0.f,0.f,0.f},{0.f,0.f,0.f,0.f}};

    // 2-deep register pipeline: e[4] + bf for kc, prefetch kc+1 during math
    float4 e[4], en[4];
    half8 bf, bfn;
#pragma unroll
    for (int jp = 0; jp < 4; ++jp) e[jp] = ((const float4*)smem)[pbase + jp];
    bf = *(const half8*)bp;

    for (int kc = 0; kc < 8; ++kc) {
        if (kc < 7) {                              // issue next-tile loads early
            bfn = *(const half8*)(bp + (kc + 1) * 32);
#pragma unroll
            for (int jp = 0; jp < 4; ++jp)
                en[jp] = ((const float4*)smem)[pbase + (kc + 1) * 16 + jp];
        }
        union { f16x2 h2[4]; half8 h8; } af[4];
#pragma unroll
        for (int jp = 0; jp < 4; ++jp) {
            union { float4 f; f16x2 h[4]; } ee; ee.f = e[jp];
#pragma unroll
            for (int s = 0; s < 4; ++s) {
                f16x2 tv = qi2[s] + ee.h[3];
                tv = __builtin_elementwise_fma(xx2[s], ee.h[0], tv);
                tv = __builtin_elementwise_fma(xy2[s], ee.h[1], tv);
                tv = __builtin_elementwise_fma(xz2[s], ee.h[2], tv);
                // threshold folded into exp arg: t'<0 -> arg <= -24 -> exp2 = 0
                f16x2 u = __builtin_elementwise_min(tv, tv * SC2);
                f16x2 r; r[0] = exph(u[0]); r[1] = exph(u[1]);
                af[s].h2[jp] = r;                  // = 10*w (2^3.32 fold)
            }
        }
#pragma unroll
        for (int s = 0; s < 4; ++s)
            acc[s] = __builtin_amdgcn_mfma_f32_16x16x32_f16(af[s].h8, bf, acc[s], 0, 0, 0);
#pragma unroll
        for (int jp = 0; jp < 4; ++jp) e[jp] = en[jp];
        bf = bfn;
    }

    // cross-wave K-reduce: red[kg 8][s 4][256] aliased over stage
    __syncthreads();
#pragma unroll
    for (int s = 0; s < 4; ++s)
        *(f32x4*)&smem[wv * 1024 + s * 256 + lane * 4] = acc[s];
    __syncthreads();

    // 2 outputs/thread: o -> n = o&15, rloc = o>>4
    const float* ihp = ihd + p * NN;
#pragma unroll
    for (int oo = 0; oo < 2; ++oo) {
        const int o = tid + oo * 512;
        const int n = o & 15, rloc = o >> 4;
        const int s = rloc >> 4, mloc = rloc & 15;
        const int base = s * 256 + (mloc >> 2) * 64 + (mloc & 3);
        float sum = 0.f;                               // = 10 * (W@B) element
#pragma unroll
        for (int g = 0; g < 8; ++g) sum += smem[g * 1024 + base + n * 4];
        const int row = m0 + rloc;
        float ihEff;
        if (FIRST) {
            float deg10 = 0.f;                         // = 10 * deg
#pragma unroll
            for (int g = 0; g < 8; ++g) deg10 += smem[g * 1024 + base + 12];
            float ih = 5.0f / deg10;                   // = 0.5/deg
            if (n == 3) ihd[p * NN + row] = ih;
            ihEff = 0.1f * ih;
        } else {
            ihEff = 0.1f * ihp[row];
        }
        float cv = (float)Bt[((size_t)p * 16 + n) * NN + row];
        float out = 0.5f * cv + ihEff * sum;
        Ct[((size_t)p * 16 + n) * NN + row] = (_Float16)out;
        if (lvl) lvl[(((size_t)p * 5 + t) * 16 + n) * NN + row] = out;
    }
}

// ---- build UT fp16 [p][16][2048]: rows 0-11 = |psi_0..3 X|, 12-15 = 0 ----
__global__ __launch_bounds__(256) void buildU_k(const float* __restrict__ Xs,
                                                const float* __restrict__ LT1,
                                                _Float16* __restrict__ UT) {
    int p = blockIdx.y;
    int m = blockIdx.x * 256 + threadIdx.x;
    const float* lp = LT1 + (size_t)p * 5 * 16 * NN;
    float4 xr = ((const float4*)Xs)[p * NN + m];
    float prev[3] = {xr.x, xr.y, xr.z};
    _Float16* ut = UT + (size_t)p * 16 * NN + m;
#pragma unroll
    for (int jw = 0; jw < 4; ++jw) {
#pragma unroll
        for (int c = 0; c < 3; ++c) {
            float nx = lp[((size_t)jw * 16 + c) * NN + m];
            ut[(3 * jw + c) * NN] = (_Float16)fabsf(prev[c] - nx);
            prev[c] = nx;
        }
    }
#pragma unroll
    for (int n = 12; n < 16; ++n) ut[n * NN] = (_Float16)0.f;
}

// ---- final mean over N of 48 features (levels [p][t][n][m]) ----
__global__ __launch_bounds__(64) void reduce_k(const float* __restrict__ Xs,
                                               const float* __restrict__ LT1,
                                               const float* __restrict__ LT2,
                                               float* __restrict__ out) {
    int f = blockIdx.x, p = blockIdx.y, lane = threadIdx.x;
    const float* l1 = LT1 + (size_t)p * 5 * 16 * NN;
    const float* l2 = LT2 + (size_t)p * 5 * 16 * NN;
    float s = 0.f;
    for (int m = lane; m < NN; m += 64) {
        float v;
        if (f < 3) {
            v = l1[((size_t)4 * 16 + f) * NN + m];
        } else if (f < 18) {
            int j = (f - 3) / 3, c = (f - 3) % 3;
            float a = (j == 0) ? Xs[((size_t)p * NN + m) * 4 + c]
                               : l1[((size_t)(j - 1) * 16 + c) * NN + m];
            float b = l1[((size_t)j * 16 + c) * NN + m];
            v = fabsf(a - b);
        } else {
            int gg = f - 18, j2, uc;
            if (gg < 3)       { j2 = 1; uc = gg; }
            else if (gg < 9)  { j2 = 2; uc = gg - 3; }
            else if (gg < 18) { j2 = 3; uc = gg - 9; }
            else              { j2 = 4; uc = gg - 18; }
            v = fabsf(l2[((size_t)(j2 - 1) * 16 + uc) * NN + m]
                    - l2[((size_t)j2 * 16 + uc) * NN + m]);
        }
        s += v;
    }
#pragma unroll
    for (int off = 32; off > 0; off >>= 1) s += __shfl_down(s, off, 64);
    if (lane == 0) out[p * 48 + f] = s * (1.0f / NN);
}

extern "C" void kernel_launch(void* const* d_in, const int* in_sizes, int n_in,
                              void* d_out, int out_size, void* d_ws, size_t ws_size,
                              hipStream_t stream) {
    const float* pc     = (const float*)d_in[0];
    const float* alphas = (const float*)d_in[1];
    float* outp = (float*)d_out;

    char* base = (char*)d_ws;
    size_t off = 0;
    auto carve = [&](size_t bytes) -> void* {
        void* r = base + off;
        off = (off + bytes + 255) & ~(size_t)255;
        return r;
    };
    float*     Xs  = (float*)carve((size_t)NPAIR * NN * 4 * sizeof(float));
    float*     Xp  = (float*)carve((size_t)NPAIR * 1024 * 4 * sizeof(float));
    float*     ihd = (float*)carve((size_t)NPAIR * NN * sizeof(float));
    _Float16*  XT  = (_Float16*)carve((size_t)NPAIR * 16 * NN * 2);
    _Float16*  UT  = (_Float16*)carve((size_t)NPAIR * 16 * NN * 2);
    _Float16*  pA  = (_Float16*)carve((size_t)NPAIR * 16 * NN * 2);
    _Float16*  pB  = (_Float16*)carve((size_t)NPAIR * 16 * NN * 2);
    float*     LT1 = (float*)carve((size_t)NPAIR * 5 * 16 * NN * sizeof(float));
    float*     LT2 = (float*)carve((size_t)NPAIR * 5 * 16 * NN * sizeof(float));

    dim3 gridA(NN / 64, NPAIR);   // 32 x 16 = 512 blocks

    init_k<<<dim3((NPAIR * NN) / 256), 256, 0, stream>>>(pc, alphas, Xs, XT);
    pack_k<<<dim3((NPAIR * 1024) / 256), 256, 0, stream>>>(Xs, Xp);

    // bank 1: B = XT (col3 = ones -> apply#1 computes deg/ihd itself)
    {
        const _Float16* cur = XT;
        int slot = 0;
        for (int step = 1; step <= 16; ++step) {
            bool sv = (step == 1 || step == 2 || step == 4 || step == 8 || step == 16);
            _Float16* o = (cur == pA) ? pB : pA;
            float* lv = sv ? LT1 : nullptr;
            if (step == 1)
                fused_apply_k<true><<<gridA, 512, 0, stream>>>(Xs, Xp, ihd, cur, o, lv, slot);
            else
                fused_apply_k<false><<<gridA, 512, 0, stream>>>(Xs, Xp, ihd, cur, o, lv, slot);
            if (sv) ++slot;
            cur = o;
        }
    }

    buildU_k<<<dim3(NN / 256, NPAIR), 256, 0, stream>>>(Xs, LT1, UT);

    // bank 2: B = UT
    {
        const _Float16* cur = UT;
        int slot = 0;
        for (int step = 1; step <= 16; ++step) {
            bool sv = (step == 1 || step == 2 || step == 4 || step == 8 || step == 16);
            _Float16* o = (cur == pA) ? pB : pA;
            fused_apply_k<false><<<gridA, 512, 0, stream>>>(Xs, Xp, ihd, cur, o,
                                                            sv ? LT2 : nullptr, slot);
            if (sv) ++slot;
            cur = o;
        }
    }

    reduce_k<<<dim3(48, NPAIR), 64, 0, stream>>>(Xs, LT1, LT2, outp);
}

// Round 14
// 553.695 us; speedup vs baseline: 1.1333x; 1.1333x over previous
//
#include <hip/hip_runtime.h>
#include <hip/hip_bf16.h>

// PointCloudNetPersistencePrediction — round 14: 8 waves/SIMD.
// R13 REGRESSED (prefetch+asm exph defeated compiler scheduling) -> reverted.
// Insight: since R6 we've been at 4 waves/SIMD (VGPR-capped). R12's ~30%
// issue efficiency at 4 waves = latency-bound; the fix is occupancy.
// Fix: s=2 m-subtiles (est ~55 VGPR <= 64), 512 thr = 8 K-waves, M=32,
// grid (64,16)=1024, LDS exactly 16KB (red aliases stage) ->
// 4 blocks/CU x 8 waves = 32 waves/CU = 8/SIMD via launch_bounds(512,8).

#define NN 2048
#define NPAIR 16

typedef _Float16 half8 __attribute__((ext_vector_type(8)));
typedef _Float16 f16x2 __attribute__((ext_vector_type(2)));
typedef float f32x4 __attribute__((ext_vector_type(4)));

extern "C" __device__ f16x2 __ocml_exp2_2f16(f16x2);   // packed v_exp_f16

#define C2F 0.28853900817779268f   //  0.2 * log2(e)
#define CWF -0.14426950408889634f  // -0.1 * log2(e)
#define NL2T 3.3219280948873623f   // -log2(0.1); qi' = qi + NL2T

// ---- init: Xs fp32 [p][i][{x,y,z,q}]; XT fp16 [p][16][2048], row3 = ones ----
__global__ __launch_bounds__(256) void init_k(const float* __restrict__ pc,
                                              const float* __restrict__ alphas,
                                              float* __restrict__ Xs,
                                              _Float16* __restrict__ XT) {
    int gid = blockIdx.x * 256 + threadIdx.x;
    if (gid >= NPAIR * NN) return;
    int p = gid >> 11, i = gid & (NN - 1);
    int b = p >> 2, k = p & 3;
    const float* pcr = pc + ((size_t)b * NN + i) * 3;
    const float* al  = alphas + k * 3;
    float x = pcr[0] * al[0], y = pcr[1] * al[1], z = pcr[2] * al[2];
    float4 o; o.x = x; o.y = y; o.z = z; o.w = CWF * (x * x + y * y + z * z);
    ((float4*)Xs)[gid] = o;
    _Float16* xt = XT + (size_t)p * 16 * NN + i;
    xt[0 * NN] = (_Float16)x;
    xt[1 * NN] = (_Float16)y;
    xt[2 * NN] = (_Float16)z;
    xt[3 * NN] = (_Float16)1.0f;          // ones column -> deg via MFMA
#pragma unroll
    for (int n = 4; n < 16; ++n) xt[n * NN] = (_Float16)0.f;
}

// ---- pack_k: Xp16[p][e] = {x2,y2,z2,q2} fp16 pairs of rows (2e, 2e+1) ----
__global__ __launch_bounds__(256) void pack_k(const float* __restrict__ Xs,
                                              float* __restrict__ Xp) {
    int gid = blockIdx.x * 256 + threadIdx.x;      // p*1024 + e
    if (gid >= NPAIR * 1024) return;
    float4 a = ((const float4*)Xs)[2 * gid];
    float4 b = ((const float4*)Xs)[2 * gid + 1];
    union { f16x2 h[4]; float4 f; } o;
    o.h[0] = (f16x2){(_Float16)a.x, (_Float16)b.x};
    o.h[1] = (f16x2){(_Float16)a.y, (_Float16)b.y};
    o.h[2] = (f16x2){(_Float16)a.z, (_Float16)b.z};
    o.h[3] = (f16x2){(_Float16)a.w, (_Float16)b.w};
    ((float4*)Xp)[gid] = o.f;
}

// ---- fused apply: Ct = f16(0.5*Bt + ihd (x) (W@Bt^T)^T), W recomputed ----
// block = 512 thr = 8 waves (K-chunk 256 each); lane owns 2 m-subtiles (M=32).
// Fragments hold 10*w; epilogue uses 0.1*ih (exact fold via 2^3.32=10).
template<bool FIRST>
__global__ __launch_bounds__(512, 8) void fused_apply_k(const float* __restrict__ Xs,
                                                        const float* __restrict__ Xp,
                                                        float* __restrict__ ihd,
                                                        const _Float16* __restrict__ Bt,
                                                        _Float16* __restrict__ Ct,
                                                        float* __restrict__ lvl,
                                                        int t) {
    __shared__ __align__(16) float smem[4096];     // 16 KB: packed X stage / red
    const int tid  = threadIdx.x;
    const int lane = tid & 63;
    const int wv   = tid >> 6;                     // K-group 0..7
    const int p    = blockIdx.y;
    const int m0   = blockIdx.x * 32;
    const int idx16 = lane & 15, quad = lane >> 4;

    // stage packed X[p] into LDS: 1024 float4 entries (2 per thread)
    {
        const float4* src = (const float4*)(Xp + (size_t)p * 1024 * 4);
        float4* dst = (float4*)smem;
        dst[tid]       = src[tid];
        dst[tid + 512] = src[tid + 512];
    }
    __syncthreads();

    // per-lane row constants (fp16 broadcast pairs), from fp32 Xs
    f16x2 qi2[2], xx2[2], xy2[2], xz2[2];
#pragma unroll
    for (int s = 0; s < 2; ++s) {
        float4 v = *(const float4*)(Xs + ((size_t)p * NN + m0 + s * 16 + idx16) * 4);
        _Float16 q = (_Float16)(v.w + NL2T);
        _Float16 x = (_Float16)(C2F * v.x);
        _Float16 y = (_Float16)(C2F * v.y);
        _Float16 z = (_Float16)(C2F * v.z);
        qi2[s] = (f16x2){q, q};
        xx2[s] = (f16x2){x, x};
        xy2[s] = (f16x2){y, y};
        xz2[s] = (f16x2){z, z};
    }
    const f16x2 SC2 = (f16x2){(_Float16)32768.f, (_Float16)32768.f};

    const _Float16* bp = Bt + ((size_t)p * 16 + idx16) * NN + wv * 256 + quad * 8;
    f32x4 acc[2] = {{0.f,0.f,0.f,0.f},{0.f,0.f,0.f,0.f}};

    for (int kc = 0; kc < 8; ++kc) {
        const int pb = wv * 128 + kc * 16 + quad * 4;  // j-pair entry base
        half8 bf = *(const half8*)(bp + kc * 32);
        union { f16x2 h2[4]; half8 h8; } af[2];
#pragma unroll
        for (int jp = 0; jp < 4; ++jp) {
            union { float4 f; f16x2 h[4]; } e;
            e.f = ((const float4*)smem)[pb + jp];      // {x2,y2,z2,q2} for 2 j
#pragma unroll
            for (int s = 0; s < 2; ++s) {
                f16x2 tv = qi2[s] + e.h[3];
                tv = __builtin_elementwise_fma(xx2[s], e.h[0], tv);
                tv = __builtin_elementwise_fma(xy2[s], e.h[1], tv);
                tv = __builtin_elementwise_fma(xz2[s], e.h[2], tv);
                // threshold folded into exp arg: t'<0 -> arg <= -24 -> exp2 = 0
                f16x2 u = __builtin_elementwise_min(tv, tv * SC2);
                af[s].h2[jp] = __ocml_exp2_2f16(u);    // = 10*w (2^3.32 fold)
            }
        }
#pragma unroll
        for (int s = 0; s < 2; ++s)
            acc[s] = __builtin_amdgcn_mfma_f32_16x16x32_f16(af[s].h8, bf, acc[s], 0, 0, 0);
    }

    // cross-wave K-reduce: red[kg 8][s 2][256] aliased over stage (4096 floats)
    __syncthreads();
#pragma unroll
    for (int s = 0; s < 2; ++s)
        *(f32x4*)&smem[wv * 512 + s * 256 + lane * 4] = acc[s];
    __syncthreads();

    // 1 output per thread: n = tid&15, rloc = tid>>4 (0..31)
    const float* ihp = ihd + p * NN;
    const int n = tid & 15, rloc = tid >> 4;
    const int s = rloc >> 4, mloc = rloc & 15;
    const int base = s * 256 + (mloc >> 2) * 64 + (mloc & 3);
    float sum = 0.f;                               // = 10 * (W@B) element
#pragma unroll
    for (int g = 0; g < 8; ++g) sum += smem[g * 512 + base + n * 4];
    const int row = m0 + rloc;
    float ihEff;
    if (FIRST) {
        float deg10 = 0.f;                         // = 10 * deg
#pragma unroll
        for (int g = 0; g < 8; ++g) deg10 += smem[g * 512 + base + 12];
        float ih = 5.0f / deg10;                   // = 0.5/deg
        if (n == 3) ihd[p * NN + row] = ih;
        ihEff = 0.1f * ih;
    } else {
        ihEff = 0.1f * ihp[row];
    }
    float cv = (float)Bt[((size_t)p * 16 + n) * NN + row];
    float out = 0.5f * cv + ihEff * sum;
    Ct[((size_t)p * 16 + n) * NN + row] = (_Float16)out;
    if (lvl) lvl[(((size_t)p * 5 + t) * 16 + n) * NN + row] = out;
}

// ---- build UT fp16 [p][16][2048]: rows 0-11 = |psi_0..3 X|, 12-15 = 0 ----
__global__ __launch_bounds__(256) void buildU_k(const float* __restrict__ Xs,
                                                const float* __restrict__ LT1,
                                                _Float16* __restrict__ UT) {
    int p = blockIdx.y;
    int m = blockIdx.x * 256 + threadIdx.x;
    const float* lp = LT1 + (size_t)p * 5 * 16 * NN;
    float4 xr = ((const float4*)Xs)[p * NN + m];
    float prev[3] = {xr.x, xr.y, xr.z};
    _Float16* ut = UT + (size_t)p * 16 * NN + m;
#pragma unroll
    for (int jw = 0; jw < 4; ++jw) {
#pragma unroll
        for (int c = 0; c < 3; ++c) {
            float nx = lp[((size_t)jw * 16 + c) * NN + m];
            ut[(3 * jw + c) * NN] = (_Float16)fabsf(prev[c] - nx);
            prev[c] = nx;
        }
    }
#pragma unroll
    for (int n = 12; n < 16; ++n) ut[n * NN] = (_Float16)0.f;
}

// ---- final mean over N of 48 features (levels [p][t][n][m]) ----
__global__ __launch_bounds__(64) void reduce_k(const float* __restrict__ Xs,
                                               const float* __restrict__ LT1,
                                               const float* __restrict__ LT2,
                                               float* __restrict__ out) {
    int f = blockIdx.x, p = blockIdx.y, lane = threadIdx.x;
    const float* l1 = LT1 + (size_t)p * 5 * 16 * NN;
    const float* l2 = LT2 + (size_t)p * 5 * 16 * NN;
    float s = 0.f;
    for (int m = lane; m < NN; m += 64) {
        float v;
        if (f < 3) {
            v = l1[((size_t)4 * 16 + f) * NN + m];
        } else if (f < 18) {
            int j = (f - 3) / 3, c = (f - 3) % 3;
            float a = (j == 0) ? Xs[((size_t)p * NN + m) * 4 + c]
                               : l1[((size_t)(j - 1) * 16 + c) * NN + m];
            float b = l1[((size_t)j * 16 + c) * NN + m];
            v = fabsf(a - b);
        } else {
            int gg = f - 18, j2, uc;
            if (gg < 3)       { j2 = 1; uc = gg; }
            else if (gg < 9)  { j2 = 2; uc = gg - 3; }
            else if (gg < 18) { j2 = 3; uc = gg - 9; }
            else              { j2 = 4; uc = gg - 18; }
            v = fabsf(l2[((size_t)(j2 - 1) * 16 + uc) * NN + m]
                    - l2[((size_t)j2 * 16 + uc) * NN + m]);
        }
        s += v;
    }
#pragma unroll
    for (int off = 32; off > 0; off >>= 1) s += __shfl_down(s, off, 64);
    if (lane == 0) out[p * 48 + f] = s * (1.0f / NN);
}

extern "C" void kernel_launch(void* const* d_in, const int* in_sizes, int n_in,
                              void* d_out, int out_size, void* d_ws, size_t ws_size,
                              hipStream_t stream) {
    const float* pc     = (const float*)d_in[0];
    const float* alphas = (const float*)d_in[1];
    float* outp = (float*)d_out;

    char* base = (char*)d_ws;
    size_t off = 0;
    auto carve = [&](size_t bytes) -> void* {
        void* r = base + off;
        off = (off + bytes + 255) & ~(size_t)255;
        return r;
    };
    float*     Xs  = (float*)carve((size_t)NPAIR * NN * 4 * sizeof(float));
    float*     Xp  = (float*)carve((size_t)NPAIR * 1024 * 4 * sizeof(float));
    float*     ihd = (float*)carve((size_t)NPAIR * NN * sizeof(float));
    _Float16*  XT  = (_Float16*)carve((size_t)NPAIR * 16 * NN * 2);
    _Float16*  UT  = (_Float16*)carve((size_t)NPAIR * 16 * NN * 2);
    _Float16*  pA  = (_Float16*)carve((size_t)NPAIR * 16 * NN * 2);
    _Float16*  pB  = (_Float16*)carve((size_t)NPAIR * 16 * NN * 2);
    float*     LT1 = (float*)carve((size_t)NPAIR * 5 * 16 * NN * sizeof(float));
    float*     LT2 = (float*)carve((size_t)NPAIR * 5 * 16 * NN * sizeof(float));

    dim3 gridA(NN / 32, NPAIR);   // 64 x 16 = 1024 blocks -> 4 blocks/CU

    init_k<<<dim3((NPAIR * NN) / 256), 256, 0, stream>>>(pc, alphas, Xs, XT);
    pack_k<<<dim3((NPAIR * 1024) / 256), 256, 0, stream>>>(Xs, Xp);

    // bank 1: B = XT (col3 = ones -> apply#1 computes deg/ihd itself)
    {
        const _Float16* cur = XT;
        int slot = 0;
        for (int step = 1; step <= 16; ++step) {
            bool sv = (step == 1 || step == 2 || step == 4 || step == 8 || step == 16);
            _Float16* o = (cur == pA) ? pB : pA;
            float* lv = sv ? LT1 : nullptr;
            if (step == 1)
                fused_apply_k<true><<<gridA, 512, 0, stream>>>(Xs, Xp, ihd, cur, o, lv, slot);
            else
                fused_apply_k<false><<<gridA, 512, 0, stream>>>(Xs, Xp, ihd, cur, o, lv, slot);
            if (sv) ++slot;
            cur = o;
        }
    }

    buildU_k<<<dim3(NN / 256, NPAIR), 256, 0, stream>>>(Xs, LT1, UT);

    // bank 2: B = UT
    {
        const _Float16* cur = UT;
        int slot = 0;
        for (int step = 1; step <= 16; ++step) {
            bool sv = (step == 1 || step == 2 || step == 4 || step == 8 || step == 16);
            _Float16* o = (cur == pA) ? pB : pA;
            fused_apply_k<false><<<gridA, 512, 0, stream>>>(Xs, Xp, ihd, cur, o,
                                                            sv ? LT2 : nullptr, slot);
            if (sv) ++slot;
            cur = o;
        }
    }

    reduce_k<<<dim3(48, NPAIR), 64, 0, stream>>>(Xs, LT1, LT2, outp);
}